// Round 3
// baseline (854.439 us; speedup 1.0000x reference)
//
#include <hip/hip_runtime.h>
#include <hip/hip_bf16.h>

#define NN    100000
#define NE    1600000
#define INCH  512
#define HIDCH 256
#define OUTCH 32
#define KHOPS 10

typedef __attribute__((ext_vector_type(8))) short short8;
typedef __attribute__((ext_vector_type(4))) float f32x4;

#define GLOAD_LDS16(gsrc, ldst) \
  __builtin_amdgcn_global_load_lds((const __attribute__((address_space(1))) void*)(gsrc), \
                                   (__attribute__((address_space(3))) void*)(ldst), 16, 0, 0)

// ---------------- workspace layout ----------------
constexpr size_t ws_align(size_t x) { return (x + 255) & ~(size_t)255; }
constexpr size_t OFF_H1   = 0;                                           // [NN][256] bf16
constexpr size_t OFF_HA   = OFF_H1   + ws_align((size_t)NN*HIDCH*2);     // [NN][32] f32
constexpr size_t OFF_HB   = OFF_HA   + ws_align((size_t)NN*OUTCH*4);     // [NN][32] f32
constexpr size_t OFF_W1TH = OFF_HB   + ws_align((size_t)NN*OUTCH*4);     // [256][512] bf16
constexpr size_t OFF_W1TL = OFF_W1TH + ws_align((size_t)HIDCH*INCH*2);
constexpr size_t OFF_W2TH = OFF_W1TL + ws_align((size_t)HIDCH*INCH*2);   // [32][256] bf16
constexpr size_t OFF_W2TL = OFF_W2TH + ws_align((size_t)OUTCH*HIDCH*2);
constexpr size_t OFF_DEG  = OFF_W2TL + ws_align((size_t)OUTCH*HIDCH*2);  // [NN] int
constexpr size_t OFF_DIS  = OFF_DEG  + ws_align((size_t)NN*4);           // [NN] f32
constexpr size_t OFF_RP   = OFF_DIS  + ws_align((size_t)NN*4);           // [NN+1] int
constexpr size_t OFF_CUR  = OFF_RP   + ws_align((size_t)(NN+1)*4);       // [NN] int
constexpr size_t OFF_EPK  = OFF_CUR  + ws_align((size_t)NN*4);           // [NE] int2 (src, norm)
constexpr size_t OFF_PART = OFF_EPK  + ws_align((size_t)NE*8);           // [128] int
constexpr size_t OFF_OFFS = OFF_PART + ws_align(512);                    // [128] int

// ---------------- bf16 helpers ----------------
__device__ __forceinline__ unsigned short bf16_rne(float f) {
  unsigned int u = __float_as_uint(f);
  u += 0x7fffu + ((u >> 16) & 1u);
  return (unsigned short)(u >> 16);
}
__device__ __forceinline__ float bf16_to_f32(unsigned short h) {
  return __uint_as_float(((unsigned int)h) << 16);
}

// ---------------- degree / norm ----------------
__global__ __launch_bounds__(256) void k_count_deg(const int* __restrict__ col,
                                                   int* __restrict__ deg) {
  int e = blockIdx.x * 256 + threadIdx.x;
  if (e < NE) atomicAdd(&deg[col[e]], 1);
}

__global__ __launch_bounds__(256) void k_dis(const int* __restrict__ deg,
                                             float* __restrict__ dis) {
  int v = blockIdx.x * 256 + threadIdx.x;
  if (v < NN) {
    int d = deg[v];
    dis[v] = d > 0 ? rsqrtf((float)d) : 0.0f;
  }
}

// ---------------- exclusive scan over deg (3 kernels) ----------------
__global__ __launch_bounds__(256) void k_scan1(const int* __restrict__ deg,
                                               int* __restrict__ rp,
                                               int* __restrict__ part) {
  __shared__ int s[256];
  int b = blockIdx.x, t = threadIdx.x;
  int base = b * 1024 + t * 4;
  int v0 = (base + 0 < NN) ? deg[base + 0] : 0;
  int v1 = (base + 1 < NN) ? deg[base + 1] : 0;
  int v2 = (base + 2 < NN) ? deg[base + 2] : 0;
  int v3 = (base + 3 < NN) ? deg[base + 3] : 0;
  int tot = v0 + v1 + v2 + v3;
  s[t] = tot;
  __syncthreads();
  for (int d = 1; d < 256; d <<= 1) {
    int x = (t >= d) ? s[t - d] : 0;
    __syncthreads();
    s[t] += x;
    __syncthreads();
  }
  int excl = s[t] - tot;
  if (t == 255) part[b] = s[255];
  if (base + 0 < NN) rp[base + 0] = excl;
  if (base + 1 < NN) rp[base + 1] = excl + v0;
  if (base + 2 < NN) rp[base + 2] = excl + v0 + v1;
  if (base + 3 < NN) rp[base + 3] = excl + v0 + v1 + v2;
}

__global__ __launch_bounds__(128) void k_scan2(const int* __restrict__ part,
                                               int* __restrict__ offs) {
  __shared__ int s[128];
  int t = threadIdx.x;
  int v = (t < 98) ? part[t] : 0;
  s[t] = v;
  __syncthreads();
  for (int d = 1; d < 128; d <<= 1) {
    int x = (t >= d) ? s[t - d] : 0;
    __syncthreads();
    s[t] += x;
    __syncthreads();
  }
  if (t < 98) offs[t] = s[t] - v;
}

__global__ __launch_bounds__(256) void k_scan3(int* __restrict__ rp,
                                               const int* __restrict__ offs,
                                               int* __restrict__ cur) {
  int b = blockIdx.x, t = threadIdx.x;
  int o = offs[b];
  int base = b * 1024 + t * 4;
#pragma unroll
  for (int j = 0; j < 4; ++j) {
    int i = base + j;
    if (i < NN) {
      int r = rp[i] + o;
      rp[i] = r;
      cur[i] = r;
    }
  }
  if (b == 0 && t == 0) rp[NN] = NE;
}

// fill CSR: epk = (src node, bits(dis[row]*dis[col]))
__global__ __launch_bounds__(256) void k_fill(const int* __restrict__ ei,
                                              const float* __restrict__ dis,
                                              int* __restrict__ cur,
                                              int2* __restrict__ epk) {
  int e = blockIdx.x * 256 + threadIdx.x;
  if (e < NE) {
    int r = ei[e], c = ei[NE + e];
    int p = atomicAdd(&cur[c], 1);
    epk[p] = make_int2(r, __float_as_int(dis[r] * dis[c]));
  }
}

// ---------------- split-transpose: dst[n][k] = split(src[k][n]) ----------------
__global__ __launch_bounds__(256) void k_splitT(const float* __restrict__ src,
                                                unsigned short* __restrict__ dh,
                                                unsigned short* __restrict__ dl,
                                                int K, int N) {
  int idx = blockIdx.x * 256 + threadIdx.x;
  if (idx >= K * N) return;
  int n = idx / K, k = idx - n * K;
  float v = src[(size_t)k * N + n];
  unsigned short h = bf16_rne(v);
  dh[idx] = h;
  dl[idx] = bf16_rne(v - bf16_to_f32(h));
}

// ---------------- GEMM1: H1bf = bf16(relu(X @ W1 + b1)), 2-product bf16 MFMA ------
// tile 128(M) x 256(N=all) x 32(K-step); 8 waves (2M x 4N), wave tile 64x64
// A: manual split+swizzled LDS write; B: global_load_lds direct (linear frag layout)
__global__ __launch_bounds__(512, 2) void k_gemm1(const float* __restrict__ X,
                                                  const unsigned short* __restrict__ W1Th,
                                                  const unsigned short* __restrict__ W1Tl,
                                                  const float* __restrict__ bias1,
                                                  unsigned short* __restrict__ H1bf) {
  // frag-packed: group g (16 rows) occupies 512 ushorts; slot=lane, 8 ushorts each
  __shared__ __align__(16) unsigned short Ah[4096];              // 8 m-groups
  __shared__ __align__(16) unsigned short Bh[8192], Bl[8192];    // 16 n-groups
  const int t = threadIdx.x;
  const int m0 = blockIdx.x * 128;
  const int w = t >> 6, lane = t & 63;
  const int wm = w >> 2, wn = w & 3;

  // A staging: thread t -> row t>>2 (0..127), k-chunk t&3 (8 floats)
  const int arow = t >> 2;
  const int achk = t & 3;
  int axrow = m0 + arow; if (axrow >= NN) axrow = NN - 1;
  const float* aptr = X + (size_t)axrow * INCH + achk * 8;
  // swizzled write index (ushorts): base idx has bits7-8 = chunk; XOR into bits 4-5
  int aidx = (arow >> 4) * 512 + ((arow & 15) + achk * 16) * 8;
  aidx ^= ((aidx >> 7) & 3) << 4;

  // A frag read offset (within group, ushorts), same swizzle
  const int aroff = (lane * 8) ^ (((lane >> 4) & 3) << 4);

  // B global source coords for global_load_lds: wave w covers groups {w, w+8}
  const int bn0 = (w * 16) + (lane & 15);        // n row for group w
  const int bko = (lane >> 4) * 8;               // k sub-offset

  f32x4 acc[4][4] = {};

  for (int k0 = 0; k0 < INCH; k0 += 32) {
    float4 av0 = *(const float4*)(aptr + k0);
    float4 av1 = *(const float4*)(aptr + k0 + 4);

    __syncthreads();  // prior MFMA reads done before LDS overwrite

    // B: 4 direct global->LDS loads per wave (Bh g, Bh g+8, Bl g, Bl g+8)
    {
      const unsigned short* s0 = W1Th + (size_t)bn0 * INCH + k0 + bko;
      const unsigned short* s1 = W1Th + (size_t)(bn0 + 128) * INCH + k0 + bko;
      const unsigned short* s2 = W1Tl + (size_t)bn0 * INCH + k0 + bko;
      const unsigned short* s3 = W1Tl + (size_t)(bn0 + 128) * INCH + k0 + bko;
      GLOAD_LDS16(s0, &Bh[w * 512]);
      GLOAD_LDS16(s1, &Bh[(w + 8) * 512]);
      GLOAD_LDS16(s2, &Bl[w * 512]);
      GLOAD_LDS16(s3, &Bl[(w + 8) * 512]);
    }

    // A: split high bf16 only, swizzled write
    {
      float af[8] = {av0.x, av0.y, av0.z, av0.w, av1.x, av1.y, av1.z, av1.w};
      short8 ah;
#pragma unroll
      for (int i = 0; i < 8; ++i) {
        unsigned int u = __float_as_uint(af[i]);
        ah[i] = (short)((u + 0x7fffu + ((u >> 16) & 1u)) >> 16);
      }
      *(short8*)&Ah[aidx] = ah;
    }

    __syncthreads();  // compiler drains vmcnt (global_load_lds) + lgkmcnt here

    short8 afrag[4];
#pragma unroll
    for (int mf = 0; mf < 4; ++mf)
      afrag[mf] = *(const short8*)&Ah[(wm * 4 + mf) * 512 + aroff];
#pragma unroll
    for (int nf = 0; nf < 4; ++nf) {
      short8 bfh = *(const short8*)&Bh[(wn * 4 + nf) * 512 + lane * 8];
      short8 bfl = *(const short8*)&Bl[(wn * 4 + nf) * 512 + lane * 8];
#pragma unroll
      for (int mf = 0; mf < 4; ++mf) {
        acc[mf][nf] = __builtin_amdgcn_mfma_f32_16x16x32_bf16(afrag[mf], bfh, acc[mf][nf], 0, 0, 0);
        acc[mf][nf] = __builtin_amdgcn_mfma_f32_16x16x32_bf16(afrag[mf], bfl, acc[mf][nf], 0, 0, 0);
      }
    }
  }

  // epilogue: +bias, relu, cvt bf16, store
  const int colbase = wn * 64 + (lane & 15);
  const int rowbase = m0 + wm * 64 + ((lane >> 4) << 2);
#pragma unroll
  for (int nf = 0; nf < 4; ++nf) {
    int col = colbase + nf * 16;
    float b = bias1[col];
#pragma unroll
    for (int mf = 0; mf < 4; ++mf) {
#pragma unroll
      for (int r = 0; r < 4; ++r) {
        int row = rowbase + mf * 16 + r;
        if (row < NN) {
          float h = fmaxf(acc[mf][nf][r] + b, 0.f);
          H1bf[(size_t)row * HIDCH + col] = bf16_rne(h);
        }
      }
    }
  }
}

// ---------------- GEMM2: h = H1bf @ W2 + b2 (2-product); hA = h; out = g0*h -------
__global__ __launch_bounds__(256) void k_gemm2(const unsigned short* __restrict__ H1bf,
                                               const unsigned short* __restrict__ W2Th,
                                               const unsigned short* __restrict__ W2Tl,
                                               const float* __restrict__ bias2,
                                               const float* __restrict__ gamma,
                                               float* __restrict__ hA,
                                               float* __restrict__ out) {
  __shared__ __align__(16) unsigned short A2[8192];
  __shared__ __align__(16) unsigned short B2h[2048], B2l[2048];
  const int t = threadIdx.x;
  const int m0 = blockIdx.x * 128;

  const int arow = t >> 1;
  int axrow = m0 + arow; if (axrow >= NN) axrow = NN - 1;
  const int akb = (t & 1) * 32;
  const unsigned short* ap = H1bf + (size_t)axrow * HIDCH + akb;
  const int abase = ((arow >> 4) * 2 + (akb >> 5)) * 512 + (arow & 15) * 8;

  const int bnr = t >> 3, bkq = (t & 7) * 8;
  const int bslot = ((bnr >> 4) * 2 + (bkq >> 5)) * 512 +
                    ((bnr & 15) + (((bkq & 31) >> 3) << 4)) * 8;
  const unsigned short* bhp = W2Th + (size_t)bnr * HIDCH + bkq;
  const unsigned short* blp = W2Tl + (size_t)bnr * HIDCH + bkq;

  const int w = t >> 6, lane = t & 63;

  f32x4 acc[2][2] = {};

  for (int k0 = 0; k0 < HIDCH; k0 += 64) {
    uint4 a0 = *(const uint4*)(ap + k0);
    uint4 a1 = *(const uint4*)(ap + k0 + 8);
    uint4 a2 = *(const uint4*)(ap + k0 + 16);
    uint4 a3 = *(const uint4*)(ap + k0 + 24);
    uint4 bh = *(const uint4*)(bhp + k0);
    uint4 bl = *(const uint4*)(blp + k0);

    __syncthreads();

    *(uint4*)&A2[abase + 0 * 128] = a0;
    *(uint4*)&A2[abase + 1 * 128] = a1;
    *(uint4*)&A2[abase + 2 * 128] = a2;
    *(uint4*)&A2[abase + 3 * 128] = a3;
    *(uint4*)&B2h[bslot] = bh;
    *(uint4*)&B2l[bslot] = bl;

    __syncthreads();

    const short8* AV  = (const short8*)A2;
    const short8* BHV = (const short8*)B2h;
    const short8* BLV = (const short8*)B2l;
#pragma unroll
    for (int k32 = 0; k32 < 2; ++k32) {
      short8 bfh[2], bfl[2];
#pragma unroll
      for (int nf = 0; nf < 2; ++nf) {
        bfh[nf] = BHV[(nf * 2 + k32) * 64 + lane];
        bfl[nf] = BLV[(nf * 2 + k32) * 64 + lane];
      }
#pragma unroll
      for (int mf = 0; mf < 2; ++mf) {
        short8 a = AV[((w * 2 + mf) * 2 + k32) * 64 + lane];
#pragma unroll
        for (int nf = 0; nf < 2; ++nf) {
          acc[mf][nf] = __builtin_amdgcn_mfma_f32_16x16x32_bf16(a, bfh[nf], acc[mf][nf], 0, 0, 0);
          acc[mf][nf] = __builtin_amdgcn_mfma_f32_16x16x32_bf16(a, bfl[nf], acc[mf][nf], 0, 0, 0);
        }
      }
    }
  }

  const float g0 = gamma[0];
  const int colb = lane & 15;
  const int rowb = m0 + w * 32 + ((lane >> 4) << 2);
#pragma unroll
  for (int nf = 0; nf < 2; ++nf) {
    int col = nf * 16 + colb;
    float b = bias2[col];
#pragma unroll
    for (int mf = 0; mf < 2; ++mf) {
#pragma unroll
      for (int r = 0; r < 4; ++r) {
        int row = rowb + mf * 16 + r;
        if (row < NN) {
          float h = acc[mf][nf][r] + b;
          hA[(size_t)row * OUTCH + col] = h;
          out[(size_t)row * OUTCH + col] = g0 * h;
        }
      }
    }
  }
}

// ---------------- one propagation hop + gamma accumulation ----------------
// one wave per node; halves take alternate edges; no per-edge shuffles.
__global__ __launch_bounds__(256) void k_hop(const float* __restrict__ hin,
                                             float* __restrict__ hout,
                                             float* __restrict__ out,
                                             const int* __restrict__ rp,
                                             const int2* __restrict__ epk,
                                             const float* __restrict__ gamma,
                                             int k) {
  const int v = blockIdx.x * 4 + (threadIdx.x >> 6);
  if (v >= NN) return;
  const int lane = threadIdx.x & 63;
  const int half = lane >> 5;
  const int c = lane & 31;
  const int s = rp[v], e = rp[v + 1];
  float acc0 = 0.f, acc1 = 0.f, acc2 = 0.f, acc3 = 0.f;
  int j = s;
  for (; j + 8 <= e; j += 8) {
    int2 a0 = epk[j + half];
    int2 a1 = epk[j + 2 + half];
    int2 a2 = epk[j + 4 + half];
    int2 a3 = epk[j + 6 + half];
    acc0 = fmaf(__int_as_float(a0.y), hin[(size_t)a0.x * OUTCH + c], acc0);
    acc1 = fmaf(__int_as_float(a1.y), hin[(size_t)a1.x * OUTCH + c], acc1);
    acc2 = fmaf(__int_as_float(a2.y), hin[(size_t)a2.x * OUTCH + c], acc2);
    acc3 = fmaf(__int_as_float(a3.y), hin[(size_t)a3.x * OUTCH + c], acc3);
  }
  for (; j + 2 <= e; j += 2) {
    int2 a0 = epk[j + half];
    acc0 = fmaf(__int_as_float(a0.y), hin[(size_t)a0.x * OUTCH + c], acc0);
  }
  if (j < e && half == 0) {
    int2 a0 = epk[j];
    acc0 = fmaf(__int_as_float(a0.y), hin[(size_t)a0.x * OUTCH + c], acc0);
  }
  float acc = (acc0 + acc1) + (acc2 + acc3);
  float oth = __shfl(acc, lane ^ 32);
  if (half == 0) {
    float tot = acc + oth;
    hout[(size_t)v * OUTCH + c] = tot;
    out[(size_t)v * OUTCH + c] += gamma[k] * tot;
  }
}

extern "C" void kernel_launch(void* const* d_in, const int* in_sizes, int n_in,
                              void* d_out, int out_size, void* d_ws, size_t ws_size,
                              hipStream_t stream) {
  const float* x     = (const float*)d_in[0];
  const int*   ei    = (const int*)d_in[1];
  const float* W1    = (const float*)d_in[2];
  const float* b1    = (const float*)d_in[3];
  const float* W2    = (const float*)d_in[4];
  const float* b2    = (const float*)d_in[5];
  const float* gamma = (const float*)d_in[6];
  float* out = (float*)d_out;

  char* ws = (char*)d_ws;
  unsigned short* h1bf = (unsigned short*)(ws + OFF_H1);
  float* hA   = (float*)(ws + OFF_HA);
  float* hB   = (float*)(ws + OFF_HB);
  unsigned short* w1th = (unsigned short*)(ws + OFF_W1TH);
  unsigned short* w1tl = (unsigned short*)(ws + OFF_W1TL);
  unsigned short* w2th = (unsigned short*)(ws + OFF_W2TH);
  unsigned short* w2tl = (unsigned short*)(ws + OFF_W2TL);
  int*   deg  = (int*)(ws + OFF_DEG);
  float* dis  = (float*)(ws + OFF_DIS);
  int*   rp   = (int*)(ws + OFF_RP);
  int*   cur  = (int*)(ws + OFF_CUR);
  int2*  epk  = (int2*)(ws + OFF_EPK);
  int*   part = (int*)(ws + OFF_PART);
  int*   offs = (int*)(ws + OFF_OFFS);

  hipMemsetAsync(deg, 0, NN * sizeof(int), stream);

  // weight prep (tiny)
  k_splitT<<<(INCH * HIDCH + 255) / 256, 256, 0, stream>>>(W1, w1th, w1tl, INCH, HIDCH);
  k_splitT<<<(HIDCH * OUTCH + 255) / 256, 256, 0, stream>>>(W2, w2th, w2tl, HIDCH, OUTCH);

  // graph prep
  k_count_deg<<<(NE + 255) / 256, 256, 0, stream>>>(ei + NE, deg);
  k_dis<<<(NN + 255) / 256, 256, 0, stream>>>(deg, dis);
  k_scan1<<<98, 256, 0, stream>>>(deg, rp, part);
  k_scan2<<<1, 128, 0, stream>>>(part, offs);
  k_scan3<<<98, 256, 0, stream>>>(rp, offs, cur);
  k_fill<<<(NE + 255) / 256, 256, 0, stream>>>(ei, dis, cur, epk);

  // MLP
  k_gemm1<<<(NN + 127) / 128, 512, 0, stream>>>(x, w1th, w1tl, b1, h1bf);
  k_gemm2<<<(NN + 127) / 128, 256, 0, stream>>>(h1bf, w2th, w2tl, b2, gamma, hA, out);

  // propagation
  float* hin = hA;
  float* hout = hB;
  for (int k = 1; k <= KHOPS; ++k) {
    k_hop<<<(NN + 3) / 4, 256, 0, stream>>>(hin, hout, out, rp, epk, gamma, k);
    float* tmp = hin; hin = hout; hout = tmp;
  }
}

// Round 4
// 625.011 us; speedup vs baseline: 1.3671x; 1.3671x over previous
//
#include <hip/hip_runtime.h>
#include <hip/hip_bf16.h>

#define NN    100000
#define NE    1600000
#define INCH  512
#define HIDCH 256
#define OUTCH 32
#define KHOPS 10

typedef __attribute__((ext_vector_type(8))) short short8;
typedef __attribute__((ext_vector_type(4))) float f32x4;

#define GLOAD_LDS16(gsrc, ldst) \
  __builtin_amdgcn_global_load_lds((const __attribute__((address_space(1))) void*)(gsrc), \
                                   (__attribute__((address_space(3))) void*)(ldst), 16, 0, 0)

// ---------------- workspace layout ----------------
constexpr size_t ws_align(size_t x) { return (x + 255) & ~(size_t)255; }
constexpr size_t OFF_H1   = 0;                                           // [NN][256] bf16
constexpr size_t OFF_HA   = OFF_H1   + ws_align((size_t)NN*HIDCH*2);     // [NN][32] bf16
constexpr size_t OFF_HB   = OFF_HA   + ws_align((size_t)NN*OUTCH*2);     // [NN][32] bf16
constexpr size_t OFF_W1TH = OFF_HB   + ws_align((size_t)NN*OUTCH*2);     // [256][512] bf16
constexpr size_t OFF_W1TL = OFF_W1TH + ws_align((size_t)HIDCH*INCH*2);
constexpr size_t OFF_W2TH = OFF_W1TL + ws_align((size_t)HIDCH*INCH*2);   // [32][256] bf16
constexpr size_t OFF_W2TL = OFF_W2TH + ws_align((size_t)OUTCH*HIDCH*2);
constexpr size_t OFF_DEG  = OFF_W2TL + ws_align((size_t)OUTCH*HIDCH*2);  // [NN] int
constexpr size_t OFF_DIS  = OFF_DEG  + ws_align((size_t)NN*4);           // [NN] f32
constexpr size_t OFF_RP   = OFF_DIS  + ws_align((size_t)NN*4);           // [NN+1] int
constexpr size_t OFF_CUR  = OFF_RP   + ws_align((size_t)(NN+1)*4);       // [NN] int
constexpr size_t OFF_EPK  = OFF_CUR  + ws_align((size_t)NN*4);           // [NE] int2 (src, norm)
constexpr size_t OFF_PART = OFF_EPK  + ws_align((size_t)NE*8);           // [128] int
constexpr size_t OFF_OFFS = OFF_PART + ws_align(512);                    // [128] int

// ---------------- bf16 helpers ----------------
__device__ __forceinline__ unsigned short bf16_rne(float f) {
  unsigned int u = __float_as_uint(f);
  u += 0x7fffu + ((u >> 16) & 1u);
  return (unsigned short)(u >> 16);
}
__device__ __forceinline__ float bf16_to_f32(unsigned short h) {
  return __uint_as_float(((unsigned int)h) << 16);
}

// ---------------- degree / norm ----------------
__global__ __launch_bounds__(256) void k_count_deg(const int* __restrict__ col,
                                                   int* __restrict__ deg) {
  int e = blockIdx.x * 256 + threadIdx.x;
  if (e < NE) atomicAdd(&deg[col[e]], 1);
}

__global__ __launch_bounds__(256) void k_dis(const int* __restrict__ deg,
                                             float* __restrict__ dis) {
  int v = blockIdx.x * 256 + threadIdx.x;
  if (v < NN) {
    int d = deg[v];
    dis[v] = d > 0 ? rsqrtf((float)d) : 0.0f;
  }
}

// ---------------- exclusive scan over deg (3 kernels) ----------------
__global__ __launch_bounds__(256) void k_scan1(const int* __restrict__ deg,
                                               int* __restrict__ rp,
                                               int* __restrict__ part) {
  __shared__ int s[256];
  int b = blockIdx.x, t = threadIdx.x;
  int base = b * 1024 + t * 4;
  int v0 = (base + 0 < NN) ? deg[base + 0] : 0;
  int v1 = (base + 1 < NN) ? deg[base + 1] : 0;
  int v2 = (base + 2 < NN) ? deg[base + 2] : 0;
  int v3 = (base + 3 < NN) ? deg[base + 3] : 0;
  int tot = v0 + v1 + v2 + v3;
  s[t] = tot;
  __syncthreads();
  for (int d = 1; d < 256; d <<= 1) {
    int x = (t >= d) ? s[t - d] : 0;
    __syncthreads();
    s[t] += x;
    __syncthreads();
  }
  int excl = s[t] - tot;
  if (t == 255) part[b] = s[255];
  if (base + 0 < NN) rp[base + 0] = excl;
  if (base + 1 < NN) rp[base + 1] = excl + v0;
  if (base + 2 < NN) rp[base + 2] = excl + v0 + v1;
  if (base + 3 < NN) rp[base + 3] = excl + v0 + v1 + v2;
}

__global__ __launch_bounds__(128) void k_scan2(const int* __restrict__ part,
                                               int* __restrict__ offs) {
  __shared__ int s[128];
  int t = threadIdx.x;
  int v = (t < 98) ? part[t] : 0;
  s[t] = v;
  __syncthreads();
  for (int d = 1; d < 128; d <<= 1) {
    int x = (t >= d) ? s[t - d] : 0;
    __syncthreads();
    s[t] += x;
    __syncthreads();
  }
  if (t < 98) offs[t] = s[t] - v;
}

__global__ __launch_bounds__(256) void k_scan3(int* __restrict__ rp,
                                               const int* __restrict__ offs,
                                               int* __restrict__ cur) {
  int b = blockIdx.x, t = threadIdx.x;
  int o = offs[b];
  int base = b * 1024 + t * 4;
#pragma unroll
  for (int j = 0; j < 4; ++j) {
    int i = base + j;
    if (i < NN) {
      int r = rp[i] + o;
      rp[i] = r;
      cur[i] = r;
    }
  }
  if (b == 0 && t == 0) rp[NN] = NE;
}

// fill CSR: epk = (src node, bits(dis[row]*dis[col]))
__global__ __launch_bounds__(256) void k_fill(const int* __restrict__ ei,
                                              const float* __restrict__ dis,
                                              int* __restrict__ cur,
                                              int2* __restrict__ epk) {
  int e = blockIdx.x * 256 + threadIdx.x;
  if (e < NE) {
    int r = ei[e], c = ei[NE + e];
    int p = atomicAdd(&cur[c], 1);
    epk[p] = make_int2(r, __float_as_int(dis[r] * dis[c]));
  }
}

// ---------------- split-transpose: dst[n][k] = split(src[k][n]) ----------------
__global__ __launch_bounds__(256) void k_splitT(const float* __restrict__ src,
                                                unsigned short* __restrict__ dh,
                                                unsigned short* __restrict__ dl,
                                                int K, int N) {
  int idx = blockIdx.x * 256 + threadIdx.x;
  if (idx >= K * N) return;
  int n = idx / K, k = idx - n * K;
  float v = src[(size_t)k * N + n];
  unsigned short h = bf16_rne(v);
  dh[idx] = h;
  dl[idx] = bf16_rne(v - bf16_to_f32(h));
}

// ---------------- GEMM1: H1bf = bf16(relu(X @ W1 + b1)), 2-product bf16 MFMA ------
// tile 128(M) x 256(N=all) x 32(K-step); 8 waves (2M x 4N), wave tile 64x64
// double-buffered LDS: prefetch tile k+1 before tile k's MFMAs, 1 barrier/iter.
__global__ __launch_bounds__(512, 2) void k_gemm1(const float* __restrict__ X,
                                                  const unsigned short* __restrict__ W1Th,
                                                  const unsigned short* __restrict__ W1Tl,
                                                  const float* __restrict__ bias1,
                                                  unsigned short* __restrict__ H1bf) {
  __shared__ __align__(16) unsigned short Ah[2][4096];             // 16 KB
  __shared__ __align__(16) unsigned short Bh[2][8192], Bl[2][8192]; // 64 KB
  const int t = threadIdx.x;
  const int m0 = blockIdx.x * 128;
  const int w = t >> 6, lane = t & 63;
  const int wm = w >> 2, wn = w & 3;

  // A staging: thread t -> row t>>2 (0..127), k-chunk t&3 (8 floats)
  const int arow = t >> 2;
  const int achk = t & 3;
  int axrow = m0 + arow; if (axrow >= NN) axrow = NN - 1;
  const float* aptr = X + (size_t)axrow * INCH + achk * 8;
  int aidx = (arow >> 4) * 512 + ((arow & 15) + achk * 16) * 8;
  aidx ^= ((aidx >> 7) & 3) << 4;                      // XOR-swizzle (verified r3: 0 conflicts)
  const int aroff = (lane * 8) ^ (((lane >> 4) & 3) << 4);

  // B global sources for global_load_lds: wave w covers n-groups {w, w+8}
  const int bn0 = (w * 16) + (lane & 15);
  const int bko = (lane >> 4) * 8;
  const unsigned short* bs0 = W1Th + (size_t)bn0 * INCH + bko;
  const unsigned short* bs1 = W1Th + (size_t)(bn0 + 128) * INCH + bko;
  const unsigned short* bs2 = W1Tl + (size_t)bn0 * INCH + bko;
  const unsigned short* bs3 = W1Tl + (size_t)(bn0 + 128) * INCH + bko;

  f32x4 acc[4][4] = {};
  float4 av0, av1;

  // ---- prologue: stage tile 0 into buffer 0 ----
  av0 = *(const float4*)(aptr);
  av1 = *(const float4*)(aptr + 4);
  GLOAD_LDS16(bs0, &Bh[0][w * 512]);
  GLOAD_LDS16(bs1, &Bh[0][(w + 8) * 512]);
  GLOAD_LDS16(bs2, &Bl[0][w * 512]);
  GLOAD_LDS16(bs3, &Bl[0][(w + 8) * 512]);
  {
    float af[8] = {av0.x, av0.y, av0.z, av0.w, av1.x, av1.y, av1.z, av1.w};
    short8 ah;
#pragma unroll
    for (int i = 0; i < 8; ++i) {
      unsigned int u = __float_as_uint(af[i]);
      ah[i] = (short)((u + 0x7fffu + ((u >> 16) & 1u)) >> 16);
    }
    *(short8*)&Ah[0][aidx] = ah;
  }
  __syncthreads();

#pragma unroll
  for (int it = 0; it < 16; ++it) {
    const int cur = it & 1, nxt = cur ^ 1;
    const int k0 = it * 32;
    // prefetch tile it+1 (issue BEFORE this tile's MFMAs; drained at end barrier)
    if (it < 15) {
      av0 = *(const float4*)(aptr + k0 + 32);
      av1 = *(const float4*)(aptr + k0 + 36);
      GLOAD_LDS16(bs0 + k0 + 32, &Bh[nxt][w * 512]);
      GLOAD_LDS16(bs1 + k0 + 32, &Bh[nxt][(w + 8) * 512]);
      GLOAD_LDS16(bs2 + k0 + 32, &Bl[nxt][w * 512]);
      GLOAD_LDS16(bs3 + k0 + 32, &Bl[nxt][(w + 8) * 512]);
    }
    // compute on buffer cur
    short8 afrag[4];
#pragma unroll
    for (int mf = 0; mf < 4; ++mf)
      afrag[mf] = *(const short8*)&Ah[cur][(wm * 4 + mf) * 512 + aroff];
#pragma unroll
    for (int nf = 0; nf < 4; ++nf) {
      short8 bfh = *(const short8*)&Bh[cur][(wn * 4 + nf) * 512 + lane * 8];
      short8 bfl = *(const short8*)&Bl[cur][(wn * 4 + nf) * 512 + lane * 8];
#pragma unroll
      for (int mf = 0; mf < 4; ++mf) {
        acc[mf][nf] = __builtin_amdgcn_mfma_f32_16x16x32_bf16(afrag[mf], bfh, acc[mf][nf], 0, 0, 0);
        acc[mf][nf] = __builtin_amdgcn_mfma_f32_16x16x32_bf16(afrag[mf], bfl, acc[mf][nf], 0, 0, 0);
      }
    }
    // A split + write for next tile (after MFMAs; only waits on its own 2 loads)
    if (it < 15) {
      float af[8] = {av0.x, av0.y, av0.z, av0.w, av1.x, av1.y, av1.z, av1.w};
      short8 ah;
#pragma unroll
      for (int i = 0; i < 8; ++i) {
        unsigned int u = __float_as_uint(af[i]);
        ah[i] = (short)((u + 0x7fffu + ((u >> 16) & 1u)) >> 16);
      }
      *(short8*)&Ah[nxt][aidx] = ah;
    }
    __syncthreads();
  }

  // epilogue: +bias, relu, cvt bf16, store
  const int colbase = wn * 64 + (lane & 15);
  const int rowbase = m0 + wm * 64 + ((lane >> 4) << 2);
#pragma unroll
  for (int nf = 0; nf < 4; ++nf) {
    int col = colbase + nf * 16;
    float b = bias1[col];
#pragma unroll
    for (int mf = 0; mf < 4; ++mf) {
#pragma unroll
      for (int r = 0; r < 4; ++r) {
        int row = rowbase + mf * 16 + r;
        if (row < NN) {
          float h = fmaxf(acc[mf][nf][r] + b, 0.f);
          H1bf[(size_t)row * HIDCH + col] = bf16_rne(h);
        }
      }
    }
  }
}

// ---------------- GEMM2: h = H1bf @ W2 + b2 (2-product); hA = bf16(h); out = g0*h -
__global__ __launch_bounds__(256) void k_gemm2(const unsigned short* __restrict__ H1bf,
                                               const unsigned short* __restrict__ W2Th,
                                               const unsigned short* __restrict__ W2Tl,
                                               const float* __restrict__ bias2,
                                               const float* __restrict__ gamma,
                                               unsigned short* __restrict__ hA,
                                               float* __restrict__ out) {
  __shared__ __align__(16) unsigned short A2[8192];
  __shared__ __align__(16) unsigned short B2h[2048], B2l[2048];
  const int t = threadIdx.x;
  const int m0 = blockIdx.x * 128;

  const int arow = t >> 1;
  int axrow = m0 + arow; if (axrow >= NN) axrow = NN - 1;
  const int akb = (t & 1) * 32;
  const unsigned short* ap = H1bf + (size_t)axrow * HIDCH + akb;
  const int abase = ((arow >> 4) * 2 + (akb >> 5)) * 512 + (arow & 15) * 8;

  const int bnr = t >> 3, bkq = (t & 7) * 8;
  const int bslot = ((bnr >> 4) * 2 + (bkq >> 5)) * 512 +
                    ((bnr & 15) + (((bkq & 31) >> 3) << 4)) * 8;
  const unsigned short* bhp = W2Th + (size_t)bnr * HIDCH + bkq;
  const unsigned short* blp = W2Tl + (size_t)bnr * HIDCH + bkq;

  const int w = t >> 6, lane = t & 63;

  f32x4 acc[2][2] = {};

  for (int k0 = 0; k0 < HIDCH; k0 += 64) {
    uint4 a0 = *(const uint4*)(ap + k0);
    uint4 a1 = *(const uint4*)(ap + k0 + 8);
    uint4 a2 = *(const uint4*)(ap + k0 + 16);
    uint4 a3 = *(const uint4*)(ap + k0 + 24);
    uint4 bh = *(const uint4*)(bhp + k0);
    uint4 bl = *(const uint4*)(blp + k0);

    __syncthreads();

    *(uint4*)&A2[abase + 0 * 128] = a0;
    *(uint4*)&A2[abase + 1 * 128] = a1;
    *(uint4*)&A2[abase + 2 * 128] = a2;
    *(uint4*)&A2[abase + 3 * 128] = a3;
    *(uint4*)&B2h[bslot] = bh;
    *(uint4*)&B2l[bslot] = bl;

    __syncthreads();

    const short8* AV  = (const short8*)A2;
    const short8* BHV = (const short8*)B2h;
    const short8* BLV = (const short8*)B2l;
#pragma unroll
    for (int k32 = 0; k32 < 2; ++k32) {
      short8 bfh[2], bfl[2];
#pragma unroll
      for (int nf = 0; nf < 2; ++nf) {
        bfh[nf] = BHV[(nf * 2 + k32) * 64 + lane];
        bfl[nf] = BLV[(nf * 2 + k32) * 64 + lane];
      }
#pragma unroll
      for (int mf = 0; mf < 2; ++mf) {
        short8 a = AV[((w * 2 + mf) * 2 + k32) * 64 + lane];
#pragma unroll
        for (int nf = 0; nf < 2; ++nf) {
          acc[mf][nf] = __builtin_amdgcn_mfma_f32_16x16x32_bf16(a, bfh[nf], acc[mf][nf], 0, 0, 0);
          acc[mf][nf] = __builtin_amdgcn_mfma_f32_16x16x32_bf16(a, bfl[nf], acc[mf][nf], 0, 0, 0);
        }
      }
    }
  }

  const float g0 = gamma[0];
  const int colb = lane & 15;
  const int rowb = m0 + w * 32 + ((lane >> 4) << 2);
#pragma unroll
  for (int nf = 0; nf < 2; ++nf) {
    int col = nf * 16 + colb;
    float b = bias2[col];
#pragma unroll
    for (int mf = 0; mf < 2; ++mf) {
#pragma unroll
      for (int r = 0; r < 4; ++r) {
        int row = rowb + mf * 16 + r;
        if (row < NN) {
          float h = acc[mf][nf][r] + b;
          hA[(size_t)row * OUTCH + col] = bf16_rne(h);
          out[(size_t)row * OUTCH + col] = g0 * h;
        }
      }
    }
  }
}

// ---------------- one propagation hop + gamma accumulation ----------------
// 8 nodes/block, half-wave (32 lanes = 32 channels) per node. Edge metadata:
// coalesced 32-edge chunk load -> LDS -> broadcast ds_read_b128 (2 edges/op).
// Producer == consumer wave => no barrier, only lgkmcnt (compiler-inserted).
__global__ __launch_bounds__(256) void k_hop(const unsigned short* __restrict__ hin,
                                             unsigned short* __restrict__ hout,
                                             float* __restrict__ out,
                                             const int* __restrict__ rp,
                                             const int2* __restrict__ epk,
                                             const float* __restrict__ gamma,
                                             int k) {
  __shared__ int2 meta[8][32];
  const int hw = threadIdx.x >> 5;
  const int c  = threadIdx.x & 31;
  const int v  = blockIdx.x * 8 + hw;
  const int s = rp[v], e = rp[v + 1];
  float acc0 = 0.f, acc1 = 0.f, acc2 = 0.f, acc3 = 0.f;
  for (int base = s; base < e; base += 32) {
    const int cnt = min(32, e - base);
    if (c < cnt) meta[hw][c] = epk[base + c];
    int j = 0;
    for (; j + 4 <= cnt; j += 4) {
      int4 q0 = *(const int4*)&meta[hw][j];
      int4 q1 = *(const int4*)&meta[hw][j + 2];
      float v0 = bf16_to_f32(hin[(size_t)q0.x * OUTCH + c]);
      float v1 = bf16_to_f32(hin[(size_t)q0.z * OUTCH + c]);
      float v2 = bf16_to_f32(hin[(size_t)q1.x * OUTCH + c]);
      float v3 = bf16_to_f32(hin[(size_t)q1.z * OUTCH + c]);
      acc0 = fmaf(__int_as_float(q0.y), v0, acc0);
      acc1 = fmaf(__int_as_float(q0.w), v1, acc1);
      acc2 = fmaf(__int_as_float(q1.y), v2, acc2);
      acc3 = fmaf(__int_as_float(q1.w), v3, acc3);
    }
    for (; j < cnt; ++j) {
      int2 m = meta[hw][j];
      acc0 = fmaf(__int_as_float(m.y), bf16_to_f32(hin[(size_t)m.x * OUTCH + c]), acc0);
    }
  }
  float tot = (acc0 + acc1) + (acc2 + acc3);
  hout[(size_t)v * OUTCH + c] = bf16_rne(tot);
  out[(size_t)v * OUTCH + c] += gamma[k] * tot;
}

extern "C" void kernel_launch(void* const* d_in, const int* in_sizes, int n_in,
                              void* d_out, int out_size, void* d_ws, size_t ws_size,
                              hipStream_t stream) {
  const float* x     = (const float*)d_in[0];
  const int*   ei    = (const int*)d_in[1];
  const float* W1    = (const float*)d_in[2];
  const float* b1    = (const float*)d_in[3];
  const float* W2    = (const float*)d_in[4];
  const float* b2    = (const float*)d_in[5];
  const float* gamma = (const float*)d_in[6];
  float* out = (float*)d_out;

  char* ws = (char*)d_ws;
  unsigned short* h1bf = (unsigned short*)(ws + OFF_H1);
  unsigned short* hA   = (unsigned short*)(ws + OFF_HA);
  unsigned short* hB   = (unsigned short*)(ws + OFF_HB);
  unsigned short* w1th = (unsigned short*)(ws + OFF_W1TH);
  unsigned short* w1tl = (unsigned short*)(ws + OFF_W1TL);
  unsigned short* w2th = (unsigned short*)(ws + OFF_W2TH);
  unsigned short* w2tl = (unsigned short*)(ws + OFF_W2TL);
  int*   deg  = (int*)(ws + OFF_DEG);
  float* dis  = (float*)(ws + OFF_DIS);
  int*   rp   = (int*)(ws + OFF_RP);
  int*   cur  = (int*)(ws + OFF_CUR);
  int2*  epk  = (int2*)(ws + OFF_EPK);
  int*   part = (int*)(ws + OFF_PART);
  int*   offs = (int*)(ws + OFF_OFFS);

  hipMemsetAsync(deg, 0, NN * sizeof(int), stream);

  // weight prep (tiny)
  k_splitT<<<(INCH * HIDCH + 255) / 256, 256, 0, stream>>>(W1, w1th, w1tl, INCH, HIDCH);
  k_splitT<<<(HIDCH * OUTCH + 255) / 256, 256, 0, stream>>>(W2, w2th, w2tl, HIDCH, OUTCH);

  // graph prep
  k_count_deg<<<(NE + 255) / 256, 256, 0, stream>>>(ei + NE, deg);
  k_dis<<<(NN + 255) / 256, 256, 0, stream>>>(deg, dis);
  k_scan1<<<98, 256, 0, stream>>>(deg, rp, part);
  k_scan2<<<1, 128, 0, stream>>>(part, offs);
  k_scan3<<<98, 256, 0, stream>>>(rp, offs, cur);
  k_fill<<<(NE + 255) / 256, 256, 0, stream>>>(ei, dis, cur, epk);

  // MLP
  k_gemm1<<<(NN + 127) / 128, 512, 0, stream>>>(x, w1th, w1tl, b1, h1bf);
  k_gemm2<<<(NN + 127) / 128, 256, 0, stream>>>(h1bf, w2th, w2tl, b2, gamma, hA, out);

  // propagation
  unsigned short* hin = hA;
  unsigned short* hout = hB;
  for (int k = 1; k <= KHOPS; ++k) {
    k_hop<<<NN / 8, 256, 0, stream>>>(hin, hout, out, rp, epk, gamma, k);
    unsigned short* tmp = hin; hin = hout; hout = tmp;
  }
}